// Round 8
// baseline (546.817 us; speedup 1.0000x reference)
//
#include <hip/hip_runtime.h>
#include <stdint.h>

typedef __bf16 bf16x8 __attribute__((ext_vector_type(8)));
typedef float  f32x4  __attribute__((ext_vector_type(4)));

#define N_JOINT 21
#define TB 2
#define REAL_ROWS 42               // 21*2
#define BATCH 16384
#define TILES 8                    // tiles per block
#define NBLK (BATCH / (TB * TILES))   // 1024 blocks = 4 per CU
#define ZLD 132                    // zbh row stride (u16)

__device__ __forceinline__ uint32_t swz(uint32_t byteoff, uint32_t row) {
  return byteoff ^ ((row & 7u) << 4);
}
__device__ __forceinline__ uint16_t f2b(float v) {
  __bf16 b = (__bf16)v;
  return __builtin_bit_cast(uint16_t, b);
}
__device__ __forceinline__ float b2f(uint16_t v) {
  uint32_t u = ((uint32_t)v) << 16;
  return __builtin_bit_cast(float, u);
}
__device__ __forceinline__ bf16x8 f2b8(float4 a, float4 b) {
  bf16x8 o;
  o[0] = (__bf16)a.x; o[1] = (__bf16)a.y; o[2] = (__bf16)a.z; o[3] = (__bf16)a.w;
  o[4] = (__bf16)b.x; o[5] = (__bf16)b.y; o[6] = (__bf16)b.z; o[7] = (__bf16)b.w;
  return o;
}

// (L z)[r][c], z bf16 in LDS row stride ZLD u16; self value in fp32 register.
__device__ __forceinline__ float lmix_h(const uint16_t* zbh, int r, int c, float zself) {
  int e = r / 21;
  int n = r - e * 21;
  const uint16_t* rowb = zbh + e * 21 * ZLD + c;
  float s = zself;
  float invd;
  if (n == 0) {
    s += b2f(rowb[1 * ZLD]) + b2f(rowb[5 * ZLD]) + b2f(rowb[9 * ZLD]) +
         b2f(rowb[13 * ZLD]) + b2f(rowb[17 * ZLD]);
    invd = 1.f / 6.f;
  } else {
    int p = (n - 1) & 3;
    if (p == 3) { s += b2f(rowb[(n - 1) * ZLD]); invd = 0.5f; }
    else {
      int left = (p == 0) ? 0 : (n - 1);
      s += b2f(rowb[left * ZLD]) + b2f(rowb[(n + 1) * ZLD]);
      invd = 1.f / 3.f;
    }
  }
  return zself - invd * s;
}
// fp32 variant for the tiny z3 buffer (stride S floats)
__device__ __forceinline__ float lmix_f(const float* zbp, int S, int r, int c, float zself) {
  int e = r / 21;
  int n = r - e * 21;
  const float* rowb = zbp + e * 21 * S + c;
  float s = zself;
  float invd;
  if (n == 0) {
    s += rowb[1 * S] + rowb[5 * S] + rowb[9 * S] + rowb[13 * S] + rowb[17 * S];
    invd = 1.f / 6.f;
  } else {
    int p = (n - 1) & 3;
    if (p == 3) { s += rowb[(n - 1) * S]; invd = 0.5f; }
    else {
      int left = (p == 0) ? 0 : (n - 1);
      s += rowb[left * S] + rowb[(n + 1) * S];
      invd = 1.f / 3.f;
    }
  }
  return zself - invd * s;
}

__device__ __forceinline__ void mixone(char* dst, const uint16_t* zbh, int r, int c,
                                       float u, float zself, float bias) {
  float h = u + lmix_h(zbh, r, c, zself) + bias;
  h = (h > 0.f) ? h : 0.01f * h;
  *(uint16_t*)(dst + swz(r * 256 + c * 2, r)) = f2b(h);
}

// ---------------- prep: fp32 weights -> bf16 frag-layout in ws ----------------
__global__ void prep_weights(const float* __restrict__ W1, const float* __restrict__ W2,
                             const float* __restrict__ W3, uint16_t* __restrict__ ws) {
  uint16_t* wf1 = ws;
  uint16_t* wf2 = ws + 65536;
  uint16_t* wf3 = ws + 65536 + 32768;
  for (int i = blockIdx.x * blockDim.x + threadIdx.x; i < 100352;
       i += gridDim.x * blockDim.x) {
    if (i < 65536) {
      int n = i >> 8, k = i & 255;
      float v = (n < 128) ? W1[k * 128 + n] : W1[32768 + k * 128 + (n - 128)];
      wf1[i] = f2b(v);
    } else if (i < 98304) {
      int j = i - 65536; int n = j >> 7, k = j & 127;
      float v = (n < 128) ? W2[k * 128 + n] : W2[16384 + k * 128 + (n - 128)];
      wf2[j] = f2b(v);
    } else {
      int j = i - 98304; int n = j >> 7, k = j & 127;
      float v = 0.f;
      if (n < 3)      v = W3[k * 3 + n];
      else if (n < 6) v = W3[384 + k * 3 + (n - 3)];
      wf3[j] = f2b(v);
    }
  }
}

#define MFMA(d, va, vb) d = __builtin_amdgcn_mfma_f32_16x16x32_bf16(va, vb, d, 0, 0, 0)

// z store (bf16), guarded for mt=2
#define ZSTH(mt, v, c) { \
  const int rb_ = mt * 16 + lk * 4; \
  zbh[(rb_ + 0) * ZLD + (c)] = f2b(v[0]); \
  zbh[(rb_ + 1) * ZLD + (c)] = f2b(v[1]); \
  zbh[(rb_ + 2) * ZLD + (c)] = f2b(v[2]); \
  zbh[(rb_ + 3) * ZLD + (c)] = f2b(v[3]); \
}
#define ZSTHG(mt, v, c) { \
  const int rb_ = mt * 16 + lk * 4; \
  if (rb_ + 0 < REAL_ROWS) zbh[(rb_ + 0) * ZLD + (c)] = f2b(v[0]); \
  if (rb_ + 1 < REAL_ROWS) zbh[(rb_ + 1) * ZLD + (c)] = f2b(v[1]); \
  if (rb_ + 2 < REAL_ROWS) zbh[(rb_ + 2) * ZLD + (c)] = f2b(v[2]); \
  if (rb_ + 3 < REAL_ROWS) zbh[(rb_ + 3) * ZLD + (c)] = f2b(v[3]); \
}
#define MIXH(dst, mt, uv, zv, c, bias) { \
  const int rb_ = mt * 16 + lk * 4; \
  mixone(dst, zbh, rb_ + 0, (c), uv[0], zv[0], bias); \
  mixone(dst, zbh, rb_ + 1, (c), uv[1], zv[1], bias); \
  mixone(dst, zbh, rb_ + 2, (c), uv[2], zv[2], bias); \
  mixone(dst, zbh, rb_ + 3, (c), uv[3], zv[3], bias); \
}
#define MIXHG(dst, mt, uv, zv, c, bias) { \
  const int rb_ = mt * 16 + lk * 4; \
  if (rb_ + 0 < REAL_ROWS) mixone(dst, zbh, rb_ + 0, (c), uv[0], zv[0], bias); \
  if (rb_ + 1 < REAL_ROWS) mixone(dst, zbh, rb_ + 1, (c), uv[1], zv[1], bias); \
  if (rb_ + 2 < REAL_ROWS) mixone(dst, zbh, rb_ + 2, (c), uv[2], zv[2], bias); \
  if (rb_ + 3 < REAL_ROWS) mixone(dst, zbh, rb_ + 3, (c), uv[3], zv[3], bias); \
}

// ---------------- fused main ----------------
// R7 -> R8: occupancy probe + latency tolerance.
//  * 256-thread blocks (4 waves x 32 cols) — tests the 1-WG/CU cap seen for 512.
//  * no sA: layer-1 A-frags loaded DIRECT from global x (fp32->bf16 in regs);
//    x re-read 4x/block but L2-served.
//  * zb in bf16 -> LDS ~35.5 KB/block -> 4 blocks/CU by LDS/threads/VGPR.
//  * same dataflow: wave-local mix, 2 barriers/tile, wave0-only layer 3.
__global__ __launch_bounds__(256)
void cheb3_main(const float* __restrict__ xp,
                const uint16_t* __restrict__ wf1, const uint16_t* __restrict__ wf2,
                const uint16_t* __restrict__ wf3,
                const float* __restrict__ b1p, const float* __restrict__ b2p,
                const float* __restrict__ b3p, float* __restrict__ outp)
{
  __shared__ __align__(16) uint16_t sH[48 * 128];    // h1 bf16, swizzled (12 KB)
  __shared__ __align__(16) uint16_t sH2[48 * 128];   // h2 bf16, swizzled (12 KB)
  __shared__ __align__(16) uint16_t zbh[REAL_ROWS * ZLD];  // z bf16 (10.8 KB)
  __shared__ float zb2[REAL_ROWS * 4];               // z3 fp32, wave0-local (0.7 KB)

  const int tid  = threadIdx.x;
  const int wid  = tid >> 6;          // 0..3
  const int lane = tid & 63;
  const int l15  = lane & 15;
  const int lk   = lane >> 4;
  char* sHc  = (char*)sH;
  char* sH2c = (char*)sH2;

  const int c0 = wid * 32 + l15;      // wave's first col block
  const int c1 = c0 + 16;             // second col block
  const float bias1a = b1p[c0], bias1b = b1p[c1];
  const float bias2a = b2p[c0], bias2b = b2p[c1];
  const float bias3  = (l15 < 3) ? b3p[l15] : 0.f;

  // zero pad rows 42..47 of sH/sH2 once (M-pad rows feed MFMA A-operands)
  {
    uint4 z16 = make_uint4(0, 0, 0, 0);
    for (int i = tid; i < (6 * 128) / 8; i += 256) {
      int f0 = i * 8, r = REAL_ROWS + (f0 >> 7), c = f0 & 127;
      *(uint4*)(sHc + swz(r * 256 + c * 2, r)) = z16;
      *(uint4*)(sH2c + swz(r * 256 + c * 2, r)) = z16;
    }
  }
  __syncthreads();

  const f32x4 zero4 = {0.f, 0.f, 0.f, 0.f};

  for (int t = 0; t < TILES; ++t) {
    const int gtile = blockIdx.x * TILES + t;
    const float* xt = xp + (size_t)gtile * (REAL_ROWS * 256);

    // ---------------- LAYER 1: x (global, direct) @ W1frag ----------------
    f32x4 ua0 = zero4, ua1 = zero4, ua2 = zero4;   // u, nt0 (cols c0)
    f32x4 ub0 = zero4, ub1 = zero4, ub2 = zero4;   // u, nt1 (cols c1)
    f32x4 za0 = zero4, za1 = zero4, za2 = zero4;   // z, nt0
    f32x4 zc0 = zero4, zc1 = zero4, zc2 = zero4;   // z, nt1
    // row addresses (mt2 clamped: rows 42..47 read row 41 garbage, discarded)
    const int r0 = l15, r1 = 16 + l15;
    const int r2 = (32 + l15 < REAL_ROWS) ? (32 + l15) : (REAL_ROWS - 1);
    #pragma unroll 1
    for (int ch = 0; ch < 8; ++ch) {
      const int ko = ch * 32 + lk * 8;
      const bf16x8 wua = *(const bf16x8*)(wf1 + c0 * 256 + ko);
      const bf16x8 wub = *(const bf16x8*)(wf1 + c1 * 256 + ko);
      const bf16x8 wza = *(const bf16x8*)(wf1 + (c0 + 128) * 256 + ko);
      const bf16x8 wzb = *(const bf16x8*)(wf1 + (c1 + 128) * 256 + ko);
      const float* x0 = xt + r0 * 256 + ko;
      const float* x1 = xt + r1 * 256 + ko;
      const float* x2 = xt + r2 * 256 + ko;
      float4 v00 = *(const float4*)(x0), v01 = *(const float4*)(x0 + 4);
      float4 v10 = *(const float4*)(x1), v11 = *(const float4*)(x1 + 4);
      float4 v20 = *(const float4*)(x2), v21 = *(const float4*)(x2 + 4);
      bf16x8 a0 = f2b8(v00, v01);
      bf16x8 a1 = f2b8(v10, v11);
      bf16x8 a2 = f2b8(v20, v21);
      MFMA(ua0, a0, wua); MFMA(ua1, a1, wua); MFMA(ua2, a2, wua);
      MFMA(ub0, a0, wub); MFMA(ub1, a1, wub); MFMA(ub2, a2, wub);
      MFMA(za0, a0, wza); MFMA(za1, a1, wza); MFMA(za2, a2, wza);
      MFMA(zc0, a0, wzb); MFMA(zc1, a1, wzb); MFMA(zc2, a2, wzb);
    }

    // mix1: wave-local z-exchange (bf16), write h1 -> sH
    ZSTH(0, za0, c0); ZSTH(1, za1, c0); ZSTHG(2, za2, c0);
    ZSTH(0, zc0, c1); ZSTH(1, zc1, c1); ZSTHG(2, zc2, c1);
    MIXH(sHc, 0, ua0, za0, c0, bias1a); MIXH(sHc, 1, ua1, za1, c0, bias1a);
    MIXHG(sHc, 2, ua2, za2, c0, bias1a);
    MIXH(sHc, 0, ub0, zc0, c1, bias1b); MIXH(sHc, 1, ub1, zc1, c1, bias1b);
    MIXHG(sHc, 2, ub2, zc2, c1, bias1b);
    __syncthreads();                          // B1: h1 visible

    // ---------------- LAYER 2: sH @ W2frag ----------------
    ua0 = zero4; ua1 = zero4; ua2 = zero4;
    ub0 = zero4; ub1 = zero4; ub2 = zero4;
    za0 = zero4; za1 = zero4; za2 = zero4;
    zc0 = zero4; zc1 = zero4; zc2 = zero4;
    #pragma unroll 1
    for (int ch = 0; ch < 4; ++ch) {
      const int ko = ch * 32 + lk * 8;
      const bf16x8 wua = *(const bf16x8*)(wf2 + c0 * 128 + ko);
      const bf16x8 wub = *(const bf16x8*)(wf2 + c1 * 128 + ko);
      const bf16x8 wza = *(const bf16x8*)(wf2 + (c0 + 128) * 128 + ko);
      const bf16x8 wzb = *(const bf16x8*)(wf2 + (c1 + 128) * 128 + ko);
      const int kb = ch * 64 + lk * 16;
      bf16x8 a0 = *(const bf16x8*)(sHc + swz((0 * 16 + l15) * 256 + kb, 0 * 16 + l15));
      bf16x8 a1 = *(const bf16x8*)(sHc + swz((1 * 16 + l15) * 256 + kb, 1 * 16 + l15));
      bf16x8 a2 = *(const bf16x8*)(sHc + swz((2 * 16 + l15) * 256 + kb, 2 * 16 + l15));
      MFMA(ua0, a0, wua); MFMA(ua1, a1, wua); MFMA(ua2, a2, wua);
      MFMA(ub0, a0, wub); MFMA(ub1, a1, wub); MFMA(ub2, a2, wub);
      MFMA(za0, a0, wza); MFMA(za1, a1, wza); MFMA(za2, a2, wza);
      MFMA(zc0, a0, wzb); MFMA(zc1, a1, wzb); MFMA(zc2, a2, wzb);
    }

    // mix2: wave-local, write h2 -> sH2
    ZSTH(0, za0, c0); ZSTH(1, za1, c0); ZSTHG(2, za2, c0);
    ZSTH(0, zc0, c1); ZSTH(1, zc1, c1); ZSTHG(2, zc2, c1);
    MIXH(sH2c, 0, ua0, za0, c0, bias2a); MIXH(sH2c, 1, ua1, za1, c0, bias2a);
    MIXHG(sH2c, 2, ua2, za2, c0, bias2a);
    MIXH(sH2c, 0, ub0, zc0, c1, bias2b); MIXH(sH2c, 1, ub1, zc1, c1, bias2b);
    MIXHG(sH2c, 2, ub2, zc2, c1, bias2b);
    __syncthreads();                          // B2: h2 visible; sH reads done

    // ---------------- LAYER 3: wave 0 only; waves 1-3 run ahead ----------------
    if (wid == 0) {
      f32x4 c30 = zero4, c31 = zero4, c32 = zero4;
      #pragma unroll 1
      for (int ch = 0; ch < 4; ++ch) {
        const bf16x8 w3_ = *(const bf16x8*)(wf3 + l15 * 128 + ch * 32 + lk * 8);
        const int kb = ch * 64 + lk * 16;
        bf16x8 a0 = *(const bf16x8*)(sH2c + swz((0 * 16 + l15) * 256 + kb, 0 * 16 + l15));
        bf16x8 a1 = *(const bf16x8*)(sH2c + swz((1 * 16 + l15) * 256 + kb, 1 * 16 + l15));
        bf16x8 a2 = *(const bf16x8*)(sH2c + swz((2 * 16 + l15) * 256 + kb, 2 * 16 + l15));
        MFMA(c30, a0, w3_); MFMA(c31, a1, w3_); MFMA(c32, a2, w3_);
      }
      if (l15 >= 3 && l15 < 6) {
        #define Z3ST(mt, v) { \
          const int rb_ = mt * 16 + lk * 4; \
          if (rb_ + 0 < REAL_ROWS) zb2[(rb_ + 0) * 4 + (l15 - 3)] = v[0]; \
          if (rb_ + 1 < REAL_ROWS) zb2[(rb_ + 1) * 4 + (l15 - 3)] = v[1]; \
          if (rb_ + 2 < REAL_ROWS) zb2[(rb_ + 2) * 4 + (l15 - 3)] = v[2]; \
          if (rb_ + 3 < REAL_ROWS) zb2[(rb_ + 3) * 4 + (l15 - 3)] = v[3]; \
        }
        Z3ST(0, c30); Z3ST(1, c31); Z3ST(2, c32);
        #undef Z3ST
      }
      if (l15 < 3) {
        #define OUT3(mt, v) { \
          const int rb_ = mt * 16 + lk * 4; \
          _Pragma("unroll") \
          for (int rg = 0; rg < 4; ++rg) { \
            int r = rb_ + rg; \
            if (r < REAL_ROWS) { \
              int e = r / 21, n = r - e * 21; \
              float zs = zb2[r * 4 + l15]; \
              float vv = v[rg] + lmix_f(zb2, 4, r, l15, zs) + bias3; \
              outp[((size_t)(gtile * TB + e) * N_JOINT + n) * 3 + l15] = vv; \
            } \
          } \
        }
        OUT3(0, c30); OUT3(1, c31); OUT3(2, c32);
        #undef OUT3
      }
    }
    // no barrier: waves 1-3 start next tile's L1 (global reads only); wave0's
    // sH2 reads finish before it joins next B1, and mix2(t+1) writes sH2 only
    // after B1(t+1). zbh WAR is same-wave program order. zb2 is wave0-private.
  }
}

extern "C" void kernel_launch(void* const* d_in, const int* in_sizes, int n_in,
                              void* d_out, int out_size, void* d_ws, size_t ws_size,
                              hipStream_t stream) {
  const float* xp  = (const float*)d_in[0];
  const float* W1p = (const float*)d_in[1];
  const float* b1p = (const float*)d_in[2];
  const float* W2p = (const float*)d_in[3];
  const float* b2p = (const float*)d_in[4];
  const float* W3p = (const float*)d_in[5];
  const float* b3p = (const float*)d_in[6];
  uint16_t* ws = (uint16_t*)d_ws;

  hipLaunchKernelGGL(prep_weights, dim3(196), dim3(512), 0, stream, W1p, W2p, W3p, ws);

  const uint16_t* wf1 = ws;
  const uint16_t* wf2 = ws + 65536;
  const uint16_t* wf3 = ws + 65536 + 32768;
  hipLaunchKernelGGL(cheb3_main, dim3(NBLK), dim3(256), 0, stream,
                     xp, wf1, wf2, wf3, b1p, b2p, b3p, (float*)d_out);
}

// Round 9
// 276.929 us; speedup vs baseline: 1.9746x; 1.9746x over previous
//
#include <hip/hip_runtime.h>
#include <stdint.h>

typedef __bf16 bf16x8 __attribute__((ext_vector_type(8)));
typedef float  f32x4  __attribute__((ext_vector_type(4)));
typedef uint16_t u16x4 __attribute__((ext_vector_type(4)));

#define N_JOINT 21
#define TB 2
#define REAL_ROWS 42               // 21*2
#define BATCH 16384
#define TILES 16
#define NBLK (BATCH / (TB * TILES))   // 512 blocks

__device__ __forceinline__ uint32_t swz(uint32_t byteoff, uint32_t row) {
  return byteoff ^ ((row & 7u) << 4);
}
__device__ __forceinline__ uint16_t f2b(float v) {
  __bf16 b = (__bf16)v;
  return __builtin_bit_cast(uint16_t, b);
}

// zt: col-major z slab [128 cols][64 rows] bf16, 8-row blocks rotated by col
// (spreads banks; reads/writes stay contiguous & aligned). elem index:
__device__ __forceinline__ uint32_t zto(int col, int row) {
  return (uint32_t)(col * 64 + ((((row >> 3) + col) & 7) << 3) + (row & 7));
}

// ---------------- prep: weights + Lhat -> bf16 frag layouts in ws ----------------
// wf1[256][256], wf2[256][128], wf3[16][128], lhat[48][64] (row-major A-source)
__global__ void prep_weights(const float* __restrict__ W1, const float* __restrict__ W2,
                             const float* __restrict__ W3, uint16_t* __restrict__ ws) {
  uint16_t* wf1  = ws;
  uint16_t* wf2  = ws + 65536;
  uint16_t* wf3  = ws + 65536 + 32768;
  uint16_t* lhat = ws + 65536 + 32768 + 2048;
  for (int i = blockIdx.x * blockDim.x + threadIdx.x; i < 103424;
       i += gridDim.x * blockDim.x) {
    if (i < 65536) {
      int n = i >> 8, k = i & 255;
      float v = (n < 128) ? W1[k * 128 + n] : W1[32768 + k * 128 + (n - 128)];
      wf1[i] = f2b(v);
    } else if (i < 98304) {
      int j = i - 65536; int n = j >> 7, k = j & 127;
      float v = (n < 128) ? W2[k * 128 + n] : W2[16384 + k * 128 + (n - 128)];
      wf2[j] = f2b(v);
    } else if (i < 100352) {
      int j = i - 98304; int n = j >> 7, k = j & 127;
      float v = 0.f;
      if (n < 3)      v = W3[k * 3 + n];
      else if (n < 6) v = W3[384 + k * 3 + (n - 3)];
      wf3[j] = f2b(v);
    } else {
      // Lhat[m][k]: block-diag (2 entities x 21 joints), L = I - D^-1 (A+I)
      int j = i - 100352; int m = j >> 6, k = j & 63;
      float v = 0.f;
      if (m < 42 && k < 42 && (m / 21 == k / 21)) {
        int n = m % 21, nk = k % 21;
        float invd = (n == 0) ? (1.f / 6.f) : ((((n - 1) & 3) == 3) ? 0.5f : (1.f / 3.f));
        if (nk == n) v = 1.f - invd;
        else {
          int pn = (n > 0) ? ((((n - 1) & 3) == 0) ? 0 : n - 1) : -1;
          int pk = (nk > 0) ? ((((nk - 1) & 3) == 0) ? 0 : nk - 1) : -1;
          if (pn == nk || pk == n) v = -invd;
        }
      }
      lhat[j] = f2b(v);
    }
  }
}

#define MFMA(d, va, vb) d = __builtin_amdgcn_mfma_f32_16x16x32_bf16(va, vb, d, 0, 0, 0)

// store 4 z values (f32x4) for mtile mt at zt col c (rows mt*16+lk*4 .. +3)
#define ZSTORE(mt, v, c) { \
  u16x4 p_; p_[0] = f2b(v[0]); p_[1] = f2b(v[1]); p_[2] = f2b(v[2]); p_[3] = f2b(v[3]); \
  *(u16x4*)(ztc + 2u * zto((c), mt * 16 + lk * 4)) = p_; \
}
// h = leaky(u' + bias) -> sH/sH2 (u' already includes L z via mix-MFMA)
#define HWR(dst, mt, uv, bias) { \
  const int rb_ = mt * 16 + lk * 4; \
  _Pragma("unroll") for (int rg_ = 0; rg_ < 4; ++rg_) { \
    int r_ = rb_ + rg_; \
    if (mt < 2 || r_ < REAL_ROWS) { \
      float h_ = uv[rg_] + bias; h_ = (h_ > 0.f) ? h_ : 0.01f * h_; \
      *(uint16_t*)(dst + swz(r_ * 256 + cu * 2, r_)) = f2b(h_); \
    } \
  } \
}

// x tile: 42 rows x 32 octs = 1344
#define PF_ISSUE(p0, p1, j, src) { \
  const int i_ = tid + j * 512; \
  const int r_ = i_ >> 5, c8_ = (i_ & 31) * 8; \
  p0 = *(const float4*)(src + r_ * 256 + c8_); \
  p1 = *(const float4*)(src + r_ * 256 + c8_ + 4); \
}
#define PF_ISSUE_G(p0, p1, j, src) { \
  const int i_ = tid + j * 512; \
  if (i_ < 1344) { \
    const int r_ = i_ >> 5, c8_ = (i_ & 31) * 8; \
    p0 = *(const float4*)(src + r_ * 256 + c8_); \
    p1 = *(const float4*)(src + r_ * 256 + c8_ + 4); \
  } \
}
#define PF_WRITE(p0, p1, j) { \
  const int i_ = tid + j * 512; \
  const int r_ = i_ >> 5, c8_ = (i_ & 31) * 8; \
  bf16x8 o_; \
  o_[0] = (__bf16)p0.x; o_[1] = (__bf16)p0.y; o_[2] = (__bf16)p0.z; o_[3] = (__bf16)p0.w; \
  o_[4] = (__bf16)p1.x; o_[5] = (__bf16)p1.y; o_[6] = (__bf16)p1.z; o_[7] = (__bf16)p1.w; \
  *(bf16x8*)(sAc + swz(r_ * 512 + c8_ * 2, r_)) = o_; \
}
#define PF_WRITE_G(p0, p1, j) { \
  const int i_ = tid + j * 512; \
  if (i_ < 1344) { \
    const int r_ = i_ >> 5, c8_ = (i_ & 31) * 8; \
    bf16x8 o_; \
    o_[0] = (__bf16)p0.x; o_[1] = (__bf16)p0.y; o_[2] = (__bf16)p0.z; o_[3] = (__bf16)p0.w; \
    o_[4] = (__bf16)p1.x; o_[5] = (__bf16)p1.y; o_[6] = (__bf16)p1.z; o_[7] = (__bf16)p1.w; \
    *(bf16x8*)(sAc + swz(r_ * 512 + c8_ * 2, r_)) = o_; \
  } \
}

// ---------------- fused main ----------------
// R8 -> R9: graph mix as MFMA. z written TRANSPOSED (zt col-major, wave-local),
// read back as B-frags (2 x ds_read_b128), Lhat A-frags preloaded (24 VGPR,
// loop-invariant) -> L*z accumulates straight into the u accumulators via 6
// MFMAs. Replaces 12 divergent scalar LDS chains per thread per mix phase.
__global__ __launch_bounds__(512)
void cheb3_main(const float* __restrict__ xp,
                const uint16_t* __restrict__ wf1, const uint16_t* __restrict__ wf2,
                const uint16_t* __restrict__ wf3, const uint16_t* __restrict__ lhp,
                const float* __restrict__ b1p, const float* __restrict__ b2p,
                const float* __restrict__ b3p, float* __restrict__ outp)
{
  __shared__ __align__(16) uint16_t sA[48 * 256];    // x bf16, swizzled (24 KB)
  __shared__ __align__(16) uint16_t sH[48 * 128];    // h1 bf16 (12 KB)
  __shared__ __align__(16) uint16_t sH2[48 * 128];   // h2 bf16 (12 KB)
  __shared__ __align__(16) uint16_t zt[128 * 64];    // z^T bf16, block-rotated (16 KB)

  const int tid  = threadIdx.x;
  const int wid  = tid >> 6;
  const int lane = tid & 63;
  const int l15  = lane & 15;
  const int lk   = lane >> 4;
  char* sAc  = (char*)sA;
  char* sHc  = (char*)sH;
  char* sH2c = (char*)sH2;
  char* ztc  = (char*)zt;

  const int cu = wid * 16 + l15;       // wave's u-column block
  const float bias1 = b1p[cu];
  const float bias2 = b2p[cu];
  const float bias3 = (l15 < 3) ? b3p[l15] : 0.f;

  // Lhat A-frags (loop-invariant, 24 VGPR): lh[mt][kc]
  const bf16x8 lh00 = *(const bf16x8*)(lhp + (0 * 16 + l15) * 64 + 0 * 32 + lk * 8);
  const bf16x8 lh01 = *(const bf16x8*)(lhp + (0 * 16 + l15) * 64 + 1 * 32 + lk * 8);
  const bf16x8 lh10 = *(const bf16x8*)(lhp + (1 * 16 + l15) * 64 + 0 * 32 + lk * 8);
  const bf16x8 lh11 = *(const bf16x8*)(lhp + (1 * 16 + l15) * 64 + 1 * 32 + lk * 8);
  const bf16x8 lh20 = *(const bf16x8*)(lhp + (2 * 16 + l15) * 64 + 0 * 32 + lk * 8);
  const bf16x8 lh21 = *(const bf16x8*)(lhp + (2 * 16 + l15) * 64 + 1 * 32 + lk * 8);

  // zero zt (rows 48..63 must be 0 forever; Lhat is 0 there but NaN*0=NaN) and
  // sA/sH/sH2 pad rows 42..47
  {
    uint4 z16 = make_uint4(0, 0, 0, 0);
    for (int i = tid; i < (128 * 64) / 8; i += 512)
      *(uint4*)(ztc + i * 16) = z16;
    for (int i = tid; i < (6 * 256) / 8; i += 512) {
      int f0 = i * 8, r = REAL_ROWS + (f0 >> 8), c = f0 & 255;
      *(uint4*)(sAc + swz(r * 512 + c * 2, r)) = z16;
    }
    for (int i = tid; i < (6 * 128) / 8; i += 512) {
      int f0 = i * 8, r = REAL_ROWS + (f0 >> 7), c = f0 & 127;
      *(uint4*)(sHc + swz(r * 256 + c * 2, r)) = z16;
      *(uint4*)(sH2c + swz(r * 256 + c * 2, r)) = z16;
    }
  }

  // stage tile 0
  {
    const float* xg = xp + (size_t)(blockIdx.x * TILES) * (REAL_ROWS * 256);
    #pragma unroll
    for (int j = 0; j < 3; ++j) {
      int i = tid + j * 512;
      if (i < 1344) {
        int r = i >> 5, c8 = (i & 31) * 8;
        float4 v0 = *(const float4*)(xg + r * 256 + c8);
        float4 v1 = *(const float4*)(xg + r * 256 + c8 + 4);
        bf16x8 o;
        o[0] = (__bf16)v0.x; o[1] = (__bf16)v0.y; o[2] = (__bf16)v0.z; o[3] = (__bf16)v0.w;
        o[4] = (__bf16)v1.x; o[5] = (__bf16)v1.y; o[6] = (__bf16)v1.z; o[7] = (__bf16)v1.w;
        *(bf16x8*)(sAc + swz(r * 512 + c8 * 2, r)) = o;
      }
    }
  }
  __syncthreads();

  const f32x4 zero4 = {0.f, 0.f, 0.f, 0.f};

  for (int t = 0; t < TILES; ++t) {
    const int gtile = blockIdx.x * TILES + t;
    const bool pf = (t + 1 < TILES);
    const float* xn = xp + (size_t)(gtile + 1) * (REAL_ROWS * 256);

    float4 pA0, pA1, pA2, pA3, pA4, pA5;
    if (pf) { PF_ISSUE(pA0, pA1, 0, xn); PF_ISSUE(pA2, pA3, 1, xn); PF_ISSUE_G(pA4, pA5, 2, xn); }

    // ---------------- LAYER 1: sA[48][256] @ W1frag ----------------
    f32x4 u0 = zero4, u1 = zero4, u2 = zero4;
    f32x4 z0 = zero4, z1 = zero4, z2 = zero4;
    #pragma unroll 2
    for (int ch = 0; ch < 8; ++ch) {
      const bf16x8 wa_ = *(const bf16x8*)(wf1 + cu * 256 + ch * 32 + lk * 8);
      const bf16x8 wb_ = *(const bf16x8*)(wf1 + (cu + 128) * 256 + ch * 32 + lk * 8);
      const int kb_ = ch * 64 + lk * 16;
      bf16x8 a0_ = *(const bf16x8*)(sAc + swz((0 * 16 + l15) * 512 + kb_, 0 * 16 + l15));
      bf16x8 a1_ = *(const bf16x8*)(sAc + swz((1 * 16 + l15) * 512 + kb_, 1 * 16 + l15));
      bf16x8 a2_ = *(const bf16x8*)(sAc + swz((2 * 16 + l15) * 512 + kb_, 2 * 16 + l15));
      MFMA(u0, a0_, wa_); MFMA(u1, a1_, wa_); MFMA(u2, a2_, wa_);
      MFMA(z0, a0_, wb_); MFMA(z1, a1_, wb_); MFMA(z2, a2_, wb_);
    }

    // mix1 (wave-local): z^T -> zt, B-frag reads, u += Lhat @ z
    ZSTORE(0, z0, cu); ZSTORE(1, z1, cu); ZSTORE(2, z2, cu);
    {
      bf16x8 bz0 = *(const bf16x8*)(ztc + 2u * zto(cu, 0 + lk * 8));
      bf16x8 bz1 = *(const bf16x8*)(ztc + 2u * zto(cu, 32 + lk * 8));
      MFMA(u0, lh00, bz0); MFMA(u0, lh01, bz1);
      MFMA(u1, lh10, bz0); MFMA(u1, lh11, bz1);
      MFMA(u2, lh20, bz0); MFMA(u2, lh21, bz1);
    }
    HWR(sHc, 0, u0, bias1); HWR(sHc, 1, u1, bias1); HWR(sHc, 2, u2, bias1);
    __syncthreads();                          // B1: h1 visible; L1 sA reads done

    if (pf) { PF_WRITE(pA0, pA1, 0); PF_WRITE(pA2, pA3, 1); PF_WRITE_G(pA4, pA5, 2); }

    // ---------------- LAYER 2: sH[48][128] @ W2frag ----------------
    u0 = zero4; u1 = zero4; u2 = zero4;
    z0 = zero4; z1 = zero4; z2 = zero4;
    #pragma unroll 2
    for (int ch = 0; ch < 4; ++ch) {
      const bf16x8 wa_ = *(const bf16x8*)(wf2 + cu * 128 + ch * 32 + lk * 8);
      const bf16x8 wb_ = *(const bf16x8*)(wf2 + (cu + 128) * 128 + ch * 32 + lk * 8);
      const int kb_ = ch * 64 + lk * 16;
      bf16x8 a0_ = *(const bf16x8*)(sHc + swz((0 * 16 + l15) * 256 + kb_, 0 * 16 + l15));
      bf16x8 a1_ = *(const bf16x8*)(sHc + swz((1 * 16 + l15) * 256 + kb_, 1 * 16 + l15));
      bf16x8 a2_ = *(const bf16x8*)(sHc + swz((2 * 16 + l15) * 256 + kb_, 2 * 16 + l15));
      MFMA(u0, a0_, wa_); MFMA(u1, a1_, wa_); MFMA(u2, a2_, wa_);
      MFMA(z0, a0_, wb_); MFMA(z1, a1_, wb_); MFMA(z2, a2_, wb_);
    }

    // mix2 (wave-local) -> sH2
    ZSTORE(0, z0, cu); ZSTORE(1, z1, cu); ZSTORE(2, z2, cu);
    {
      bf16x8 bz0 = *(const bf16x8*)(ztc + 2u * zto(cu, 0 + lk * 8));
      bf16x8 bz1 = *(const bf16x8*)(ztc + 2u * zto(cu, 32 + lk * 8));
      MFMA(u0, lh00, bz0); MFMA(u0, lh01, bz1);
      MFMA(u1, lh10, bz0); MFMA(u1, lh11, bz1);
      MFMA(u2, lh20, bz0); MFMA(u2, lh21, bz1);
    }
    HWR(sH2c, 0, u0, bias2); HWR(sH2c, 1, u1, bias2); HWR(sH2c, 2, u2, bias2);
    __syncthreads();                          // B2: h2 visible; L2 sH reads + sA writes done

    // ---------------- LAYER 3: wave 0 only; waves 1-7 run ahead ----------------
    if (wid == 0) {
      f32x4 c30 = zero4, c31 = zero4, c32 = zero4;
      #pragma unroll 1
      for (int ch = 0; ch < 4; ++ch) {
        const bf16x8 w3_ = *(const bf16x8*)(wf3 + l15 * 128 + ch * 32 + lk * 8);
        const int kb_ = ch * 64 + lk * 16;
        bf16x8 a0_ = *(const bf16x8*)(sH2c + swz((0 * 16 + l15) * 256 + kb_, 0 * 16 + l15));
        bf16x8 a1_ = *(const bf16x8*)(sH2c + swz((1 * 16 + l15) * 256 + kb_, 1 * 16 + l15));
        bf16x8 a2_ = *(const bf16x8*)(sH2c + swz((2 * 16 + l15) * 256 + kb_, 2 * 16 + l15));
        MFMA(c30, a0_, w3_); MFMA(c31, a1_, w3_); MFMA(c32, a2_, w3_);
      }
      // z3 (acc cols 3..5) -> zt cols 0..2 (wave0's slab; mix2 reads already done)
      if (l15 >= 3 && l15 < 6) {
        ZSTORE(0, c30, l15 - 3); ZSTORE(1, c31, l15 - 3); ZSTORE(2, c32, l15 - 3);
      }
      {
        bf16x8 b30 = *(const bf16x8*)(ztc + 2u * zto(l15, 0 + lk * 8));
        bf16x8 b31 = *(const bf16x8*)(ztc + 2u * zto(l15, 32 + lk * 8));
        MFMA(c30, lh00, b30); MFMA(c30, lh01, b31);
        MFMA(c31, lh10, b30); MFMA(c31, lh11, b31);
        MFMA(c32, lh20, b30); MFMA(c32, lh21, b31);
      }
      if (l15 < 3) {
        #define OUT3(mt, v) { \
          const int rb_ = mt * 16 + lk * 4; \
          _Pragma("unroll") \
          for (int rg = 0; rg < 4; ++rg) { \
            int r = rb_ + rg; \
            if (r < REAL_ROWS) { \
              int e = r / 21, n = r - e * 21; \
              outp[((size_t)(gtile * TB + e) * N_JOINT + n) * 3 + l15] = v[rg] + bias3; \
            } \
          } \
        }
        OUT3(0, c30); OUT3(1, c31); OUT3(2, c32);
        #undef OUT3
      }
    }
    // no barrier: zt/z3 traffic is wave-local; waves 1-7 proceed to next tile's
    // L1 (their own zt slabs + sA reads finish before next B1 ordering).
  }
}

extern "C" void kernel_launch(void* const* d_in, const int* in_sizes, int n_in,
                              void* d_out, int out_size, void* d_ws, size_t ws_size,
                              hipStream_t stream) {
  const float* xp  = (const float*)d_in[0];
  const float* W1p = (const float*)d_in[1];
  const float* b1p = (const float*)d_in[2];
  const float* W2p = (const float*)d_in[3];
  const float* b2p = (const float*)d_in[4];
  const float* W3p = (const float*)d_in[5];
  const float* b3p = (const float*)d_in[6];
  uint16_t* ws = (uint16_t*)d_ws;

  hipLaunchKernelGGL(prep_weights, dim3(202), dim3(512), 0, stream, W1p, W2p, W3p, ws);

  const uint16_t* wf1 = ws;
  const uint16_t* wf2 = ws + 65536;
  const uint16_t* wf3 = ws + 65536 + 32768;
  const uint16_t* lhp = ws + 65536 + 32768 + 2048;
  hipLaunchKernelGGL(cheb3_main, dim3(NBLK), dim3(512), 0, stream,
                     xp, wf1, wf2, wf3, lhp, b1p, b2p, b3p, (float*)d_out);
}

// Round 10
// 227.177 us; speedup vs baseline: 2.4070x; 1.2190x over previous
//
#include <hip/hip_runtime.h>
#include <stdint.h>

typedef __bf16 bf16x8 __attribute__((ext_vector_type(8)));
typedef float  f32x4  __attribute__((ext_vector_type(4)));
typedef uint16_t u16x4 __attribute__((ext_vector_type(4)));

#define N_JOINT 21
#define TB 2
#define REAL_ROWS 42               // 21*2
#define BATCH 16384
#define TILES 32
#define NBLK (BATCH / (TB * TILES))   // 256 blocks = 1 per CU, single round

__device__ __forceinline__ uint32_t swz(uint32_t byteoff, uint32_t row) {
  return byteoff ^ ((row & 7u) << 4);
}
__device__ __forceinline__ uint16_t f2b(float v) {
  __bf16 b = (__bf16)v;
  return __builtin_bit_cast(uint16_t, b);
}

// zt: col-major z slab [cols][64 rows] bf16, 8-row blocks rotated by col
__device__ __forceinline__ uint32_t zto(int col, int row) {
  return (uint32_t)(col * 64 + ((((row >> 3) + col) & 7) << 3) + (row & 7));
}

// ---------------- prep: weights + Lhat -> bf16 frag layouts in ws ----------------
__global__ void prep_weights(const float* __restrict__ W1, const float* __restrict__ W2,
                             const float* __restrict__ W3, uint16_t* __restrict__ ws) {
  uint16_t* wf1  = ws;
  uint16_t* wf2  = ws + 65536;
  uint16_t* wf3  = ws + 65536 + 32768;
  uint16_t* lhat = ws + 65536 + 32768 + 2048;
  for (int i = blockIdx.x * blockDim.x + threadIdx.x; i < 103424;
       i += gridDim.x * blockDim.x) {
    if (i < 65536) {
      int n = i >> 8, k = i & 255;
      float v = (n < 128) ? W1[k * 128 + n] : W1[32768 + k * 128 + (n - 128)];
      wf1[i] = f2b(v);
    } else if (i < 98304) {
      int j = i - 65536; int n = j >> 7, k = j & 127;
      float v = (n < 128) ? W2[k * 128 + n] : W2[16384 + k * 128 + (n - 128)];
      wf2[j] = f2b(v);
    } else if (i < 100352) {
      int j = i - 98304; int n = j >> 7, k = j & 127;
      float v = 0.f;
      if (n < 3)      v = W3[k * 3 + n];
      else if (n < 6) v = W3[384 + k * 3 + (n - 3)];
      wf3[j] = f2b(v);
    } else {
      // Lhat[m][k]: block-diag (2 entities x 21 joints), L = I - D^-1 (A+I)
      int j = i - 100352; int m = j >> 6, k = j & 63;
      float v = 0.f;
      if (m < 42 && k < 42 && (m / 21 == k / 21)) {
        int n = m % 21, nk = k % 21;
        float invd = (n == 0) ? (1.f / 6.f) : ((((n - 1) & 3) == 3) ? 0.5f : (1.f / 3.f));
        if (nk == n) v = 1.f - invd;
        else {
          int pn = (n > 0) ? ((((n - 1) & 3) == 0) ? 0 : n - 1) : -1;
          int pk = (nk > 0) ? ((((nk - 1) & 3) == 0) ? 0 : nk - 1) : -1;
          if (pn == nk || pk == n) v = -invd;
        }
      }
      lhat[j] = f2b(v);
    }
  }
}

#define MFMA(d, va, vb) d = __builtin_amdgcn_mfma_f32_16x16x32_bf16(va, vb, d, 0, 0, 0)

// store 4 z values (f32x4) for mtile mt at col c of slab `base` (char*)
#define ZSTORE(base, mt, v, c) { \
  u16x4 p_; p_[0] = f2b(v[0]); p_[1] = f2b(v[1]); p_[2] = f2b(v[2]); p_[3] = f2b(v[3]); \
  *(u16x4*)((base) + 2u * zto((c), mt * 16 + lk * 4)) = p_; \
}
// h = leaky(u' + bias) -> sH/sH2 (u' already includes L z via mix-MFMA)
#define HWR(dst, mt, uv, bias) { \
  const int rb_ = mt * 16 + lk * 4; \
  _Pragma("unroll") for (int rg_ = 0; rg_ < 4; ++rg_) { \
    int r_ = rb_ + rg_; \
    if (mt < 2 || r_ < REAL_ROWS) { \
      float h_ = uv[rg_] + bias; h_ = (h_ > 0.f) ? h_ : 0.01f * h_; \
      *(uint16_t*)(dst + swz(r_ * 256 + cu * 2, r_)) = f2b(h_); \
    } \
  } \
}

// x tile: 42 rows x 32 octs = 1344
#define PF_ISSUE(p0, p1, j, src) { \
  const int i_ = tid + j * 512; \
  const int r_ = i_ >> 5, c8_ = (i_ & 31) * 8; \
  p0 = *(const float4*)(src + r_ * 256 + c8_); \
  p1 = *(const float4*)(src + r_ * 256 + c8_ + 4); \
}
#define PF_ISSUE_G(p0, p1, j, src) { \
  const int i_ = tid + j * 512; \
  if (i_ < 1344) { \
    const int r_ = i_ >> 5, c8_ = (i_ & 31) * 8; \
    p0 = *(const float4*)(src + r_ * 256 + c8_); \
    p1 = *(const float4*)(src + r_ * 256 + c8_ + 4); \
  } \
}
#define PF_WRITE(p0, p1, j) { \
  const int i_ = tid + j * 512; \
  const int r_ = i_ >> 5, c8_ = (i_ & 31) * 8; \
  bf16x8 o_; \
  o_[0] = (__bf16)p0.x; o_[1] = (__bf16)p0.y; o_[2] = (__bf16)p0.z; o_[3] = (__bf16)p0.w; \
  o_[4] = (__bf16)p1.x; o_[5] = (__bf16)p1.y; o_[6] = (__bf16)p1.z; o_[7] = (__bf16)p1.w; \
  *(bf16x8*)(sAc + swz(r_ * 512 + c8_ * 2, r_)) = o_; \
}
#define PF_WRITE_G(p0, p1, j) { \
  const int i_ = tid + j * 512; \
  if (i_ < 1344) { \
    const int r_ = i_ >> 5, c8_ = (i_ & 31) * 8; \
    bf16x8 o_; \
    o_[0] = (__bf16)p0.x; o_[1] = (__bf16)p0.y; o_[2] = (__bf16)p0.z; o_[3] = (__bf16)p0.w; \
    o_[4] = (__bf16)p1.x; o_[5] = (__bf16)p1.y; o_[6] = (__bf16)p1.z; o_[7] = (__bf16)p1.w; \
    *(bf16x8*)(sAc + swz(r_ * 512 + c8_ * 2, r_)) = o_; \
  } \
}

// ---------------- fused main ----------------
// R9 -> R10: (1) L3 duty rotates across waves (wid == t&7) with a dedicated
// zt3 slab -> the per-tile solo phase no longer accumulates on one SIMD;
// (2) deeper weight-load pipelining (L1 unroll 4, L2 full) -> more L2 loads
// in flight; (3) TILES 32 / NBLK 256 -> single block round.
__global__ __launch_bounds__(512)
void cheb3_main(const float* __restrict__ xp,
                const uint16_t* __restrict__ wf1, const uint16_t* __restrict__ wf2,
                const uint16_t* __restrict__ wf3, const uint16_t* __restrict__ lhp,
                const float* __restrict__ b1p, const float* __restrict__ b2p,
                const float* __restrict__ b3p, float* __restrict__ outp)
{
  __shared__ __align__(16) uint16_t sA[48 * 256];    // x bf16, swizzled (24 KB)
  __shared__ __align__(16) uint16_t sH[48 * 128];    // h1 bf16 (12 KB)
  __shared__ __align__(16) uint16_t sH2[48 * 128];   // h2 bf16 (12 KB)
  __shared__ __align__(16) uint16_t zt[128 * 64];    // z^T bf16, block-rotated (16 KB)
  __shared__ __align__(16) uint16_t zt3[16 * 64];    // z3^T slab for L3 wave (2 KB)

  const int tid  = threadIdx.x;
  const int wid  = tid >> 6;
  const int lane = tid & 63;
  const int l15  = lane & 15;
  const int lk   = lane >> 4;
  char* sAc  = (char*)sA;
  char* sHc  = (char*)sH;
  char* sH2c = (char*)sH2;
  char* ztc  = (char*)zt;
  char* zt3c = (char*)zt3;

  const int cu = wid * 16 + l15;       // wave's u-column block
  const float bias1 = b1p[cu];
  const float bias2 = b2p[cu];
  const float bias3 = (l15 < 3) ? b3p[l15] : 0.f;

  // Lhat A-frags (loop-invariant, 24 VGPR): lh[mt][kc]
  const bf16x8 lh00 = *(const bf16x8*)(lhp + (0 * 16 + l15) * 64 + 0 * 32 + lk * 8);
  const bf16x8 lh01 = *(const bf16x8*)(lhp + (0 * 16 + l15) * 64 + 1 * 32 + lk * 8);
  const bf16x8 lh10 = *(const bf16x8*)(lhp + (1 * 16 + l15) * 64 + 0 * 32 + lk * 8);
  const bf16x8 lh11 = *(const bf16x8*)(lhp + (1 * 16 + l15) * 64 + 1 * 32 + lk * 8);
  const bf16x8 lh20 = *(const bf16x8*)(lhp + (2 * 16 + l15) * 64 + 0 * 32 + lk * 8);
  const bf16x8 lh21 = *(const bf16x8*)(lhp + (2 * 16 + l15) * 64 + 1 * 32 + lk * 8);

  // zero zt + zt3 (rows 48..63 / unused cols must stay 0: garbage could be NaN
  // and MFMA computes all 16 cols even if discarded... B garbage only affects
  // discarded C cols, but rows>47 of used cols DO contribute -> keep 0) and
  // sA/sH/sH2 pad rows 42..47
  {
    uint4 z16 = make_uint4(0, 0, 0, 0);
    for (int i = tid; i < (128 * 64) / 8; i += 512)
      *(uint4*)(ztc + i * 16) = z16;
    for (int i = tid; i < (16 * 64) / 8; i += 512)
      *(uint4*)(zt3c + i * 16) = z16;
    for (int i = tid; i < (6 * 256) / 8; i += 512) {
      int f0 = i * 8, r = REAL_ROWS + (f0 >> 8), c = f0 & 255;
      *(uint4*)(sAc + swz(r * 512 + c * 2, r)) = z16;
    }
    for (int i = tid; i < (6 * 128) / 8; i += 512) {
      int f0 = i * 8, r = REAL_ROWS + (f0 >> 7), c = f0 & 127;
      *(uint4*)(sHc + swz(r * 256 + c * 2, r)) = z16;
      *(uint4*)(sH2c + swz(r * 256 + c * 2, r)) = z16;
    }
  }

  // stage tile 0
  {
    const float* xg = xp + (size_t)(blockIdx.x * TILES) * (REAL_ROWS * 256);
    #pragma unroll
    for (int j = 0; j < 3; ++j) {
      int i = tid + j * 512;
      if (i < 1344) {
        int r = i >> 5, c8 = (i & 31) * 8;
        float4 v0 = *(const float4*)(xg + r * 256 + c8);
        float4 v1 = *(const float4*)(xg + r * 256 + c8 + 4);
        bf16x8 o;
        o[0] = (__bf16)v0.x; o[1] = (__bf16)v0.y; o[2] = (__bf16)v0.z; o[3] = (__bf16)v0.w;
        o[4] = (__bf16)v1.x; o[5] = (__bf16)v1.y; o[6] = (__bf16)v1.z; o[7] = (__bf16)v1.w;
        *(bf16x8*)(sAc + swz(r * 512 + c8 * 2, r)) = o;
      }
    }
  }
  __syncthreads();

  const f32x4 zero4 = {0.f, 0.f, 0.f, 0.f};

  for (int t = 0; t < TILES; ++t) {
    const int gtile = blockIdx.x * TILES + t;
    const bool pf = (t + 1 < TILES);
    const float* xn = xp + (size_t)(gtile + 1) * (REAL_ROWS * 256);

    float4 pA0, pA1, pA2, pA3, pA4, pA5;
    if (pf) { PF_ISSUE(pA0, pA1, 0, xn); PF_ISSUE(pA2, pA3, 1, xn); PF_ISSUE_G(pA4, pA5, 2, xn); }

    // ---------------- LAYER 1: sA[48][256] @ W1frag ----------------
    f32x4 u0 = zero4, u1 = zero4, u2 = zero4;
    f32x4 z0 = zero4, z1 = zero4, z2 = zero4;
    #pragma unroll 4
    for (int ch = 0; ch < 8; ++ch) {
      const bf16x8 wa_ = *(const bf16x8*)(wf1 + cu * 256 + ch * 32 + lk * 8);
      const bf16x8 wb_ = *(const bf16x8*)(wf1 + (cu + 128) * 256 + ch * 32 + lk * 8);
      const int kb_ = ch * 64 + lk * 16;
      bf16x8 a0_ = *(const bf16x8*)(sAc + swz((0 * 16 + l15) * 512 + kb_, 0 * 16 + l15));
      bf16x8 a1_ = *(const bf16x8*)(sAc + swz((1 * 16 + l15) * 512 + kb_, 1 * 16 + l15));
      bf16x8 a2_ = *(const bf16x8*)(sAc + swz((2 * 16 + l15) * 512 + kb_, 2 * 16 + l15));
      MFMA(u0, a0_, wa_); MFMA(u1, a1_, wa_); MFMA(u2, a2_, wa_);
      MFMA(z0, a0_, wb_); MFMA(z1, a1_, wb_); MFMA(z2, a2_, wb_);
    }

    // mix1 (wave-local): z^T -> zt, B-frag reads, u += Lhat @ z
    ZSTORE(ztc, 0, z0, cu); ZSTORE(ztc, 1, z1, cu); ZSTORE(ztc, 2, z2, cu);
    {
      bf16x8 bz0 = *(const bf16x8*)(ztc + 2u * zto(cu, 0 + lk * 8));
      bf16x8 bz1 = *(const bf16x8*)(ztc + 2u * zto(cu, 32 + lk * 8));
      MFMA(u0, lh00, bz0); MFMA(u0, lh01, bz1);
      MFMA(u1, lh10, bz0); MFMA(u1, lh11, bz1);
      MFMA(u2, lh20, bz0); MFMA(u2, lh21, bz1);
    }
    HWR(sHc, 0, u0, bias1); HWR(sHc, 1, u1, bias1); HWR(sHc, 2, u2, bias1);
    __syncthreads();                          // B1: h1 visible; L1 sA reads done

    if (pf) { PF_WRITE(pA0, pA1, 0); PF_WRITE(pA2, pA3, 1); PF_WRITE_G(pA4, pA5, 2); }

    // ---------------- LAYER 2: sH[48][128] @ W2frag ----------------
    u0 = zero4; u1 = zero4; u2 = zero4;
    z0 = zero4; z1 = zero4; z2 = zero4;
    #pragma unroll
    for (int ch = 0; ch < 4; ++ch) {
      const bf16x8 wa_ = *(const bf16x8*)(wf2 + cu * 128 + ch * 32 + lk * 8);
      const bf16x8 wb_ = *(const bf16x8*)(wf2 + (cu + 128) * 128 + ch * 32 + lk * 8);
      const int kb_ = ch * 64 + lk * 16;
      bf16x8 a0_ = *(const bf16x8*)(sHc + swz((0 * 16 + l15) * 256 + kb_, 0 * 16 + l15));
      bf16x8 a1_ = *(const bf16x8*)(sHc + swz((1 * 16 + l15) * 256 + kb_, 1 * 16 + l15));
      bf16x8 a2_ = *(const bf16x8*)(sHc + swz((2 * 16 + l15) * 256 + kb_, 2 * 16 + l15));
      MFMA(u0, a0_, wa_); MFMA(u1, a1_, wa_); MFMA(u2, a2_, wa_);
      MFMA(z0, a0_, wb_); MFMA(z1, a1_, wb_); MFMA(z2, a2_, wb_);
    }

    // mix2 (wave-local) -> sH2
    ZSTORE(ztc, 0, z0, cu); ZSTORE(ztc, 1, z1, cu); ZSTORE(ztc, 2, z2, cu);
    {
      bf16x8 bz0 = *(const bf16x8*)(ztc + 2u * zto(cu, 0 + lk * 8));
      bf16x8 bz1 = *(const bf16x8*)(ztc + 2u * zto(cu, 32 + lk * 8));
      MFMA(u0, lh00, bz0); MFMA(u0, lh01, bz1);
      MFMA(u1, lh10, bz0); MFMA(u1, lh11, bz1);
      MFMA(u2, lh20, bz0); MFMA(u2, lh21, bz1);
    }
    HWR(sH2c, 0, u0, bias2); HWR(sH2c, 1, u1, bias2); HWR(sH2c, 2, u2, bias2);
    __syncthreads();                          // B2: h2 visible; L2 sH reads + sA writes done

    // ---------------- LAYER 3: rotating wave (t&7); others run ahead ----------------
    if (wid == (t & 7)) {
      f32x4 c30 = zero4, c31 = zero4, c32 = zero4;
      #pragma unroll 2
      for (int ch = 0; ch < 4; ++ch) {
        const bf16x8 w3_ = *(const bf16x8*)(wf3 + l15 * 128 + ch * 32 + lk * 8);
        const int kb_ = ch * 64 + lk * 16;
        bf16x8 a0_ = *(const bf16x8*)(sH2c + swz((0 * 16 + l15) * 256 + kb_, 0 * 16 + l15));
        bf16x8 a1_ = *(const bf16x8*)(sH2c + swz((1 * 16 + l15) * 256 + kb_, 1 * 16 + l15));
        bf16x8 a2_ = *(const bf16x8*)(sH2c + swz((2 * 16 + l15) * 256 + kb_, 2 * 16 + l15));
        MFMA(c30, a0_, w3_); MFMA(c31, a1_, w3_); MFMA(c32, a2_, w3_);
      }
      // z3 (acc cols 3..5) -> zt3 cols 0..2 (L3-wave private; WAR across tiles
      // ordered by B2 barriers)
      if (l15 >= 3 && l15 < 6) {
        ZSTORE(zt3c, 0, c30, l15 - 3); ZSTORE(zt3c, 1, c31, l15 - 3); ZSTORE(zt3c, 2, c32, l15 - 3);
      }
      {
        bf16x8 b30 = *(const bf16x8*)(zt3c + 2u * zto(l15, 0 + lk * 8));
        bf16x8 b31 = *(const bf16x8*)(zt3c + 2u * zto(l15, 32 + lk * 8));
        MFMA(c30, lh00, b30); MFMA(c30, lh01, b31);
        MFMA(c31, lh10, b30); MFMA(c31, lh11, b31);
        MFMA(c32, lh20, b30); MFMA(c32, lh21, b31);
      }
      if (l15 < 3) {
        #define OUT3(mt, v) { \
          const int rb_ = mt * 16 + lk * 4; \
          _Pragma("unroll") \
          for (int rg = 0; rg < 4; ++rg) { \
            int r = rb_ + rg; \
            if (r < REAL_ROWS) { \
              int e = r / 21, n = r - e * 21; \
              outp[((size_t)(gtile * TB + e) * N_JOINT + n) * 3 + l15] = v[rg] + bias3; \
            } \
          } \
        }
        OUT3(0, c30); OUT3(1, c31); OUT3(2, c32);
        #undef OUT3
      }
    }
    // no barrier: zt/zt3 traffic is wave-local; other waves proceed to next
    // tile's L1 (their zt slabs + sA reads finish before next B1 ordering).
  }
}

extern "C" void kernel_launch(void* const* d_in, const int* in_sizes, int n_in,
                              void* d_out, int out_size, void* d_ws, size_t ws_size,
                              hipStream_t stream) {
  const float* xp  = (const float*)d_in[0];
  const float* W1p = (const float*)d_in[1];
  const float* b1p = (const float*)d_in[2];
  const float* W2p = (const float*)d_in[3];
  const float* b2p = (const float*)d_in[4];
  const float* W3p = (const float*)d_in[5];
  const float* b3p = (const float*)d_in[6];
  uint16_t* ws = (uint16_t*)d_ws;

  hipLaunchKernelGGL(prep_weights, dim3(202), dim3(512), 0, stream, W1p, W2p, W3p, ws);

  const uint16_t* wf1 = ws;
  const uint16_t* wf2 = ws + 65536;
  const uint16_t* wf3 = ws + 65536 + 32768;
  const uint16_t* lhp = ws + 65536 + 32768 + 2048;
  hipLaunchKernelGGL(cheb3_main, dim3(NBLK), dim3(512), 0, stream,
                     xp, wf1, wf2, wf3, lhp, b1p, b2p, b3p, (float*)d_out);
}